// Round 17
// baseline (96.572 us; speedup 1.0000x reference)
//
#include <hip/hip_runtime.h>
#include <hip/hip_bf16.h>
#include <cstdint>
#include <cstddef>

// ---------------------------------------------------------------------------
// Types / helpers
// ---------------------------------------------------------------------------
typedef __bf16 bf16x8 __attribute__((ext_vector_type(8)));
typedef float  f32x4  __attribute__((ext_vector_type(4)));

template <int V> struct IC { static constexpr int value = V; };

__device__ __forceinline__ unsigned short f2bf(float f) {
    unsigned x = __float_as_uint(f);
    return (unsigned short)((x + 0x7fffu + ((x >> 16) & 1u)) >> 16); // RNE
}

__device__ __forceinline__ f32x4 mfma16(bf16x8 a, bf16x8 b, f32x4 c) {
    return __builtin_amdgcn_mfma_f32_16x16x32_bf16(a, b, c, 0, 0, 0);
}

// XOR-swizzled byte offset inside an LDS tile with 128-byte rows (64-col bf16).
__device__ __forceinline__ int swz(int row, int col) {
    return row * 128 + ((((col >> 3) ^ (row & 7)) << 4) | ((col & 7) << 1));
}

// BK-parameterized tile swizzle. BK=64: 8 slots/row. BK=32: 4 slots/row.
template <int BK>
__device__ __forceinline__ int tswz(int row, int col) {
    if constexpr (BK == 64)
        return row * 128 + ((((col >> 3) ^ (row & 7)) << 4) | ((col & 7) << 1));
    else
        return row * 64 + ((((col >> 3) ^ ((row >> 1) & 3)) << 4) | ((col & 7) << 1));
}

// global -> LDS direct copy, 16B per lane; lds ptr must be wave-uniform base.
#define GLDS16(g, l)                                                          \
    __builtin_amdgcn_global_load_lds(                                         \
        (const __attribute__((address_space(1))) void*)(g),                   \
        (__attribute__((address_space(3))) void*)(l), 16, 0, 0)

// ---------------------------------------------------------------------------
// Combined prep: blocks [0,12288) = fp32->bf16 convert of q/k/v rows (one
// 1024-elem row per block; K/V rows >= valid_len skipped — dead downstream);
// blocks [12288,16384) = 32x32 transpose+convert tiles of the 4 weights.
// ---------------------------------------------------------------------------
__global__ __launch_bounds__(256) void k_prep(const float4* __restrict__ i0,
                                              const float4* __restrict__ i1,
                                              const float4* __restrict__ i2,
                                              ushort4* __restrict__ xout,
                                              const float* __restrict__ W0,
                                              const float* __restrict__ W1,
                                              const float* __restrict__ W2,
                                              const float* __restrict__ W3,
                                              unsigned short* __restrict__ wout,
                                              int D, const int* __restrict__ vlen) {
    __shared__ float tile[32][33];
    const int bid = blockIdx.x;
    if (bid < 12288) {  // X convert: z = tensor, row = bid % 4096
        int z = bid >> 12, rowb = bid & 4095;
        if (z) {  // k,v: skip rows >= valid_len[batch]
            if ((rowb & 1023) >= vlen[rowb >> 10]) return;
        }
        const float4* in = (z == 0) ? i0 : (z == 1) ? i1 : i2;
        int i = rowb * 256 + threadIdx.x;
        float4 v = in[i];
        ushort4 o;
        o.x = f2bf(v.x); o.y = f2bf(v.y); o.z = f2bf(v.z); o.w = f2bf(v.w);
        xout[(size_t)z * 1048576 + i] = o;
    } else {            // weight transpose+convert
        int wid = bid - 12288;
        int z = wid >> 10, t2 = wid & 1023;
        int bx = t2 & 31, by = t2 >> 5;
        const float* W = (z == 0) ? W0 : (z == 1) ? W1 : (z == 2) ? W2 : W3;
        unsigned short* Wt = wout + (size_t)z * D * D;
        int c0 = bx * 32, r0 = by * 32;
        int tr = threadIdx.x >> 5, tc = threadIdx.x & 31;
#pragma unroll
        for (int i = 0; i < 4; i++)
            tile[tr + 8 * i][tc] = W[(size_t)(r0 + tr + 8 * i) * D + c0 + tc];
        __syncthreads();
#pragma unroll
        for (int i = 0; i < 4; i++)
            Wt[(size_t)(c0 + tr + 8 * i) * D + r0 + tc] = f2bf(tile[tc][tr + 8 * i]);
    }
}

// ---------------------------------------------------------------------------
// 256x256-tile 8-phase bf16 GEMM (batched over z=QKV): P_z = X_z * Wt_z^T.
// 512 thr / 8 waves (2M x 4N); wave tile 128x64; BK=64, 2 K-tiles/iter;
// 128 KB LDS (2 tile buffers, XOR-swizzled); counted vmcnt(4) at phases 4/8.
// ---------------------------------------------------------------------------
__global__ __launch_bounds__(512, 2) void k_gemm8(const unsigned short* __restrict__ A0,
                                                  const unsigned short* __restrict__ Bt0,
                                                  unsigned short* __restrict__ C0,
                                                  int M, int N, int K,
                                                  size_t aStr, size_t bStr, size_t cStr,
                                                  const int* __restrict__ vlen) {
    __shared__ unsigned short As[2][256 * 64];  // 32 KB each
    __shared__ unsigned short Bs[2][256 * 64];

    const int gxy = gridDim.x * gridDim.y;
    const int nwg = gxy * gridDim.z;
    int wgid = blockIdx.z * gxy + blockIdx.y * gridDim.x + blockIdx.x;
    int sid = (wgid & 7) * (nwg >> 3) + (wgid >> 3);
    const int bz = sid / gxy;
    int rem = sid - bz * gxy;
    const int by = rem / gridDim.x;
    const int bx = rem - by * gridDim.x;

    if (bz >= 1) {
        int srow = (by << 8) & 1023;
        int bb = (by << 8) >> 10;
        if (srow >= vlen[bb]) return;
    }

    const unsigned short* A  = A0 + (size_t)bz * aStr;
    const unsigned short* Bt = Bt0 + (size_t)bz * bStr;
    unsigned short* C = C0 + (size_t)bz * cStr;

    const int t = threadIdx.x, lane = t & 63, w = t >> 6;
    const int wr = w >> 2, wc = w & 3;
    const int l15 = lane & 15, l4 = lane >> 4;
    const int brow = by * 256, bcol = bx * 256;

    f32x4 acc[8][4];
#pragma unroll
    for (int m = 0; m < 8; m++)
#pragma unroll
        for (int n = 0; n < 4; n++) acc[m][n] = f32x4{0.f, 0.f, 0.f, 0.f};

    auto stA = [&](int buf, int kt, int h) {
#pragma unroll
        for (int j = 0; j < 2; j++) {
            int c = h * 1024 + j * 512 + t;
            int row = c >> 3, slot = c & 7;
            GLDS16(A + (size_t)(brow + row) * K + kt * 64 + ((slot ^ (row & 7)) << 3),
                   (char*)As[buf] + (size_t)(h * 1024 + j * 512 + w * 64) * 16);
        }
    };
    auto stB = [&](int buf, int kt, int h) {
#pragma unroll
        for (int j = 0; j < 2; j++) {
            int c = h * 1024 + j * 512 + t;
            int row = c >> 3, slot = c & 7;
            GLDS16(Bt + (size_t)(bcol + row) * K + kt * 64 + ((slot ^ (row & 7)) << 3),
                   (char*)Bs[buf] + (size_t)(h * 1024 + j * 512 + w * 64) * 16);
        }
    };

    bf16x8 b[4][2];

    auto phase = [&](auto BUFC, auto GC, auto RBC, auto stage, auto VMC) {
        constexpr int BUF = BUFC.value, G = GC.value, VM = VMC.value;
        constexpr bool RB = RBC.value != 0;
        bf16x8 a[2][2];
#pragma unroll
        for (int i = 0; i < 2; i++)
#pragma unroll
            for (int ks = 0; ks < 2; ks++)
                a[i][ks] = *(const bf16x8*)((const char*)As[BUF] +
                           swz(wr * 128 + (2 * G + i) * 16 + l15, ks * 32 + l4 * 8));
        if constexpr (RB) {
#pragma unroll
            for (int nf = 0; nf < 4; nf++)
#pragma unroll
                for (int ks = 0; ks < 2; ks++)
                    b[nf][ks] = *(const bf16x8*)((const char*)Bs[BUF] +
                                swz(wc * 64 + nf * 16 + l15, ks * 32 + l4 * 8));
        }
        stage();
        __builtin_amdgcn_s_barrier();
        asm volatile("s_waitcnt lgkmcnt(0)" ::: "memory");
        __builtin_amdgcn_sched_barrier(0);
        __builtin_amdgcn_s_setprio(1);
#pragma unroll
        for (int i = 0; i < 2; i++)
#pragma unroll
            for (int nf = 0; nf < 4; nf++)
#pragma unroll
                for (int ks = 0; ks < 2; ks++)
                    acc[2 * G + i][nf] = mfma16(a[i][ks], b[nf][ks], acc[2 * G + i][nf]);
        __builtin_amdgcn_s_setprio(0);
        if constexpr (VM == 0) {
            asm volatile("s_waitcnt vmcnt(0)" ::: "memory");
            __builtin_amdgcn_sched_barrier(0);
        } else if constexpr (VM > 0) {
            asm volatile("s_waitcnt vmcnt(4)" ::: "memory");
            __builtin_amdgcn_sched_barrier(0);
        }
        __builtin_amdgcn_s_barrier();
    };

    auto iter = [&](int t0, auto LASTC) {
        constexpr bool LAST = LASTC.value != 0;
        phase(IC<0>{}, IC<0>{}, IC<1>{}, [&] { stA(1, t0 + 1, 0); }, IC<-1>{});
        phase(IC<0>{}, IC<1>{}, IC<0>{}, [&] { stA(1, t0 + 1, 1); }, IC<-1>{});
        phase(IC<0>{}, IC<2>{}, IC<0>{}, [&] { if constexpr (!LAST) stB(0, t0 + 2, 0); }, IC<-1>{});
        phase(IC<0>{}, IC<3>{}, IC<0>{}, [&] { if constexpr (!LAST) stB(0, t0 + 2, 1); },
              IC<LAST ? 0 : 4>{});
        phase(IC<1>{}, IC<0>{}, IC<1>{}, [&] { if constexpr (!LAST) stA(0, t0 + 2, 0); }, IC<-1>{});
        phase(IC<1>{}, IC<1>{}, IC<0>{}, [&] { if constexpr (!LAST) stA(0, t0 + 2, 1); }, IC<-1>{});
        phase(IC<1>{}, IC<2>{}, IC<0>{}, [&] { if constexpr (!LAST) stB(1, t0 + 3, 0); }, IC<-1>{});
        phase(IC<1>{}, IC<3>{}, IC<0>{}, [&] { if constexpr (!LAST) stB(1, t0 + 3, 1); },
              IC<LAST ? -1 : 4>{});
    };

    stA(0, 0, 0); stA(0, 0, 1);
    stB(0, 0, 0); stB(0, 0, 1);
    stB(1, 1, 0); stB(1, 1, 1);
    __syncthreads();

    const int NIT = K >> 7;
    for (int it = 0; it < NIT - 1; ++it) iter(2 * it, IC<0>{});
    iter(2 * (NIT - 1), IC<1>{});

#pragma unroll
    for (int mf = 0; mf < 8; mf++)
#pragma unroll
        for (int nf = 0; nf < 4; nf++)
#pragma unroll
            for (int r = 0; r < 4; r++) {
                int row = brow + wr * 128 + mf * 16 + l4 * 4 + r;
                int col = bcol + wc * 64 + nf * 16 + l15;
                C[(size_t)row * N + col] = f2bf(acc[mf][nf][r]);
            }
}

// ---------------------------------------------------------------------------
// 2-phase GEMM (Wo): tile 128 x TN, BK=32/64, dbuf LDS, prefetch.
// ---------------------------------------------------------------------------
template <int BK, int TN, typename OutT>
__global__ __launch_bounds__(256) void k_gemm_bt(const unsigned short* __restrict__ A0,
                                                 const unsigned short* __restrict__ Bt0,
                                                 OutT* __restrict__ C0,
                                                 int M, int N, int K,
                                                 size_t aStr, size_t bStr, size_t cStr) {
    constexpr int NF = TN / 32;
    constexpr int SLOTS = BK / 8;
    constexpr int RA = BK / 16;
    constexpr int RB = TN * BK / 2048;

    __shared__ unsigned short As[2][128 * BK];
    __shared__ unsigned short Bs[2][TN * BK];

    const int gxy = gridDim.x * gridDim.y;
    const int nwg = gxy * gridDim.z;
    int wgid = blockIdx.z * gxy + blockIdx.y * gridDim.x + blockIdx.x;
    int sid = (wgid & 7) * (nwg >> 3) + (wgid >> 3);
    const int bz = sid / gxy;
    int rem = sid - bz * gxy;
    const int by = rem / gridDim.x;
    const int bx = rem - by * gridDim.x;

    const unsigned short* A  = A0 + (size_t)bz * aStr;
    const unsigned short* Bt = Bt0 + (size_t)bz * bStr;
    OutT* C = C0 + (size_t)bz * cStr;

    const int t = threadIdx.x;
    const int lane = t & 63, wave = t >> 6;
    const int wr = wave >> 1, wc = wave & 1;
    const int l15 = lane & 15, l4 = lane >> 4;
    const int brow = by * 128, bcol = bx * TN;

    f32x4 zero = {0.f, 0.f, 0.f, 0.f};
    f32x4 acc[4][NF];
#pragma unroll
    for (int m = 0; m < 4; m++)
#pragma unroll
        for (int n = 0; n < NF; n++) acc[m][n] = zero;

    auto stage = [&](int buf, int k0) {
#pragma unroll
        for (int i = 0; i < RA; i++) {
            int c = t + i * 256;
            int row = c / SLOTS;
            int slot = c & (SLOTS - 1);
            int gx = (BK == 64) ? (row & 7) : ((row >> 1) & 3);
            GLDS16(A + (size_t)(brow + row) * K + k0 + (slot ^ gx) * 8,
                   (char*)As[buf] + (size_t)((wave * 64 + i * 256) * 16));
        }
#pragma unroll
        for (int i = 0; i < RB; i++) {
            int c = t + i * 256;
            int row = c / SLOTS;
            int slot = c & (SLOTS - 1);
            int gx = (BK == 64) ? (row & 7) : ((row >> 1) & 3);
            GLDS16(Bt + (size_t)(bcol + row) * K + k0 + (slot ^ gx) * 8,
                   (char*)Bs[buf] + (size_t)((wave * 64 + i * 256) * 16));
        }
    };

    auto compute = [&](int buf) {
#pragma unroll
        for (int ks = 0; ks < BK / 32; ++ks) {
            bf16x8 a[4], b[NF];
#pragma unroll
            for (int m = 0; m < 4; m++) {
                int row = wr * 64 + m * 16 + l15;
                a[m] = *(const bf16x8*)((const char*)As[buf] + tswz<BK>(row, ks * 32 + l4 * 8));
            }
#pragma unroll
            for (int n = 0; n < NF; n++) {
                int row = wc * (TN / 2) + n * 16 + l15;
                b[n] = *(const bf16x8*)((const char*)Bs[buf] + tswz<BK>(row, ks * 32 + l4 * 8));
            }
            __builtin_amdgcn_s_setprio(1);
#pragma unroll
            for (int m = 0; m < 4; m++)
#pragma unroll
                for (int n = 0; n < NF; n++)
                    acc[m][n] = mfma16(a[m], b[n], acc[m][n]);
            __builtin_amdgcn_s_setprio(0);
        }
    };

    const int NT = K / BK;
    stage(0, 0);
    __syncthreads();
    int cur = 0;
    for (int kt = 0; kt < NT - 1; ++kt) {
        stage(cur ^ 1, (kt + 1) * BK);
        compute(cur);
        __syncthreads();
        cur ^= 1;
    }
    compute(cur);

#pragma unroll
    for (int m = 0; m < 4; m++)
#pragma unroll
        for (int n = 0; n < NF; n++)
#pragma unroll
            for (int r = 0; r < 4; r++) {
                int row = brow + wr * 64 + m * 16 + l4 * 4 + r;
                int col = bcol + wc * (TN / 2) + n * 16 + l15;
                float v = acc[m][n][r];
                if constexpr (sizeof(OutT) == 2)
                    ((unsigned short*)C)[(size_t)row * N + col] = f2bf(v);
                else
                    C[(size_t)row * N + col] = v;
            }
}

// ---------------------------------------------------------------------------
// Fused flash attention, one block per (b, h, 64 q-rows). 256 thr, 4 waves.
// Balanced XCD-locality remap: XCD k (wgid%8==k) owns pairs (b, h%8==k) ->
// 8 K/V panels (~2MB) per XCD-L2, 2 pairs per batch (vl-balanced).
// T13 defer-max: skip O-rescale when max-growth <= 8 (P bounded by e^8).
// ---------------------------------------------------------------------------
__global__ __launch_bounds__(256) void k_attn(const unsigned short* __restrict__ Qp,
                                              const unsigned short* __restrict__ Kp,
                                              const unsigned short* __restrict__ Vp,
                                              const int* __restrict__ valid_lens,
                                              unsigned short* __restrict__ AO,
                                              int S, int D) {
    __shared__ unsigned short Ks[2][64 * 64];
    __shared__ unsigned short Vt[2][64 * 64];
    __shared__ unsigned short Ps[64 * 64];

    const int t = threadIdx.x, lane = t & 63, w = t >> 6;
    const int l15 = lane & 15, l4 = lane >> 4;

    // balanced XCD remap (grid 16x16x4 = 1024 blocks)
    const int wgid = blockIdx.z * 256 + blockIdx.y * 16 + blockIdx.x;
    const int slot = wgid >> 3, pl = slot >> 4;
    const int b = pl >> 1;
    const int h = ((pl & 1) << 3) | (wgid & 7);
    const int q0 = (slot & 15) * 64;

    const int vl = valid_lens[b];
    const size_t baserow = (size_t)b * S;
    const int hcol = h * 64;
    const int vr = t >> 2, vc0 = (t & 3) * 16;

    bf16x8 aq[2];
#pragma unroll
    for (int ks = 0; ks < 2; ++ks)
        aq[ks] = *(const bf16x8*)&Qp[(baserow + q0 + w * 16 + l15) * D + hcol + ks * 32 + l4 * 8];

    f32x4 zero = {0.f, 0.f, 0.f, 0.f};
    f32x4 oacc[4];
#pragma unroll
    for (int nf = 0; nf < 4; nf++) oacc[nf] = zero;
    float m_run[4], l_run[4];
#pragma unroll
    for (int r = 0; r < 4; r++) { m_run[r] = -1e30f; l_run[r] = 0.f; }

    auto stageK = [&](int buf, int kv0) {
#pragma unroll
        for (int i = 0; i < 2; i++) {
            int c = t + i * 256;
            int row = c >> 3;
            int gcol = ((c & 7) ^ (row & 7)) * 8;
            const unsigned short* gk = Kp + (baserow + kv0 + row) * D + hcol + gcol;
            GLDS16(gk, (char*)Ks[buf] + (size_t)((w * 64 + i * 256) * 16));
        }
    };
    auto loadV = [&](int kv0, bf16x8& v0, bf16x8& v1) {
        const unsigned short* gv = Vp + (baserow + kv0 + vr) * D + hcol + vc0;
        v0 = *(const bf16x8*)gv;
        v1 = *(const bf16x8*)(gv + 8);
    };
    auto writeV = [&](int buf, bf16x8 v0, bf16x8 v1) {
#pragma unroll
        for (int i = 0; i < 8; i++) {
            union { __bf16 h; unsigned short u; } c0, c1;
            c0.h = v0[i]; c1.h = v1[i];
            *(unsigned short*)((char*)Vt[buf] + swz(vc0 + i, vr)) = c0.u;
            *(unsigned short*)((char*)Vt[buf] + swz(vc0 + 8 + i, vr)) = c1.u;
        }
    };

    const int nt = (vl + 63) >> 6;
    stageK(0, 0);
    {
        bf16x8 v0, v1;
        loadV(0, v0, v1);
        writeV(0, v0, v1);
    }

    int cur = 0;
    for (int tt = 0; tt < nt; ++tt) {
        __syncthreads();

        bf16x8 nv0, nv1;
        const bool have_next = (tt + 1) < nt;
        if (have_next) {
            stageK(cur ^ 1, (tt + 1) * 64);
            loadV((tt + 1) * 64, nv0, nv1);
        }

        const int kv0 = tt * 64;
        f32x4 sacc[4];
#pragma unroll
        for (int f = 0; f < 4; f++) {
            sacc[f] = zero;
#pragma unroll
            for (int ks = 0; ks < 2; ++ks) {
                bf16x8 bk = *(const bf16x8*)((const char*)Ks[cur] + swz(f * 16 + l15, ks * 32 + l4 * 8));
                __builtin_amdgcn_s_setprio(1);
                sacc[f] = mfma16(aq[ks], bk, sacc[f]);
                __builtin_amdgcn_s_setprio(0);
            }
        }
#pragma unroll
        for (int f = 0; f < 4; f++) {
            bool masked = (kv0 + f * 16 + l15) >= vl;
#pragma unroll
            for (int r = 0; r < 4; r++) {
                float s = sacc[f][r] * 0.125f;
                sacc[f][r] = masked ? -1e30f : s;
            }
        }
        float mx[4];
#pragma unroll
        for (int r = 0; r < 4; r++)
            mx[r] = fmaxf(fmaxf(sacc[0][r], sacc[1][r]), fmaxf(sacc[2][r], sacc[3][r]));
#pragma unroll
        for (int off = 1; off < 16; off <<= 1)
#pragma unroll
            for (int r = 0; r < 4; r++) mx[r] = fmaxf(mx[r], __shfl_xor(mx[r], off));

        // T13 defer-max: wave-uniform skip of the rescale pass
        float dmax = fmaxf(fmaxf(mx[0] - m_run[0], mx[1] - m_run[1]),
                           fmaxf(mx[2] - m_run[2], mx[3] - m_run[3]));
        if (!__all(dmax <= 8.0f)) {
#pragma unroll
            for (int r = 0; r < 4; r++) {
                float nm = fmaxf(m_run[r], mx[r]);
                float alpha = __expf(m_run[r] - nm);
                m_run[r] = nm;
                l_run[r] *= alpha;
#pragma unroll
                for (int nf = 0; nf < 4; nf++) oacc[nf][r] *= alpha;
            }
        }

        float rs[4];
#pragma unroll
        for (int r = 0; r < 4; r++) rs[r] = 0.f;
#pragma unroll
        for (int f = 0; f < 4; f++)
#pragma unroll
            for (int r = 0; r < 4; r++) {
                float p = __expf(sacc[f][r] - m_run[r]);
                rs[r] += p;
                *(unsigned short*)((char*)Ps + swz(w * 16 + l4 * 4 + r, f * 16 + l15)) = f2bf(p);
            }
#pragma unroll
        for (int off = 1; off < 16; off <<= 1)
#pragma unroll
            for (int r = 0; r < 4; r++) rs[r] += __shfl_xor(rs[r], off);
#pragma unroll
        for (int r = 0; r < 4; r++) l_run[r] += rs[r];

        if (have_next) writeV(cur ^ 1, nv0, nv1);

        asm volatile("s_waitcnt lgkmcnt(0)" ::: "memory");
        __builtin_amdgcn_sched_barrier(0);

        bf16x8 ap[2];
#pragma unroll
        for (int ks = 0; ks < 2; ++ks)
            ap[ks] = *(const bf16x8*)((const char*)Ps + swz(w * 16 + l15, ks * 32 + l4 * 8));
#pragma unroll
        for (int nf = 0; nf < 4; nf++)
#pragma unroll
            for (int ks = 0; ks < 2; ++ks) {
                bf16x8 bv = *(const bf16x8*)((const char*)Vt[cur] + swz(nf * 16 + l15, ks * 32 + l4 * 8));
                __builtin_amdgcn_s_setprio(1);
                oacc[nf] = mfma16(ap[ks], bv, oacc[nf]);
                __builtin_amdgcn_s_setprio(0);
            }
        cur ^= 1;
    }

#pragma unroll
    for (int nf = 0; nf < 4; nf++)
#pragma unroll
        for (int r = 0; r < 4; r++) {
            float v = oacc[nf][r] / l_run[r];
            int row = q0 + w * 16 + l4 * 4 + r;
            AO[(baserow + row) * D + hcol + nf * 16 + l15] = f2bf(v);
        }
}

// ---------------------------------------------------------------------------
// Launch
// ---------------------------------------------------------------------------
extern "C" void kernel_launch(void* const* d_in, const int* in_sizes, int n_in,
                              void* d_out, int out_size, void* d_ws, size_t ws_size,
                              hipStream_t stream) {
    const float* q  = (const float*)d_in[0];
    const float* k  = (const float*)d_in[1];
    const float* v  = (const float*)d_in[2];
    const int* vlen = (const int*)d_in[3];
    const float* Wq = (const float*)d_in[4];
    const float* Wk = (const float*)d_in[5];
    const float* Wv = (const float*)d_in[6];
    const float* Wo = (const float*)d_in[7];

    const int B = in_sizes[3];        // 4
    const int D = 1024, S = 1024, H = 16;  // fixed problem instance (dh=64)
    const int M = B * S;              // 4096
    const size_t MB = 1u << 20;

    char* ws = (char*)d_ws;
    unsigned short* X   = (unsigned short*)(ws + 0 * MB);   // Xq,Xk,Xv contiguous (8MB each)
    unsigned short* Wt  = (unsigned short*)(ws + 24 * MB);  // Wtq,Wtk,Wtv,Wto contiguous (2MB each)
    unsigned short* Wto = (unsigned short*)(ws + 30 * MB);
    unsigned short* P   = (unsigned short*)(ws + 32 * MB);  // Qp,Kp,Vp contiguous (8MB each)
    unsigned short* Qp  = P;
    unsigned short* Kp  = P + 4 * 1024 * 1024;
    unsigned short* Vp  = P + 8 * 1024 * 1024;
    unsigned short* AO  = X;  // safe: X dead after QKV projections

    // prep: X converts (K/V dead rows skipped) + weight transposes, 1 launch
    k_prep<<<dim3(16384), 256, 0, stream>>>(
        (const float4*)q, (const float4*)k, (const float4*)v, (ushort4*)X,
        Wq, Wk, Wv, Wo, Wt, D, vlen);

    // QKV projections: 256^2 8-phase kernel, z=3 (192 blocks), dead K/V tiles skipped
    const size_t xStr = (size_t)M * D, wStr = (size_t)D * D;
    k_gemm8<<<dim3(D / 256, M / 256, 3), 512, 0, stream>>>(
        X, Wt, P, M, D, D, xStr, wStr, xStr, vlen);

    // attention: 64 q-rows per block (1024 blocks, 4/CU TLP, XCD-local K/V)
    k_attn<<<dim3(S / 64, H, B), 256, 0, stream>>>(Qp, Kp, Vp, vlen, AO, S, D);

    // output projection (fp32 out): tile 128x64, BK=64, 512 blocks = 2/CU.
    k_gemm_bt<64, 64, float><<<dim3(D / 64, M / 128, 1), 256, 0, stream>>>(
        AO, Wto, (float*)d_out, M, D, D, 0, 0, 0);
}

// Round 18
// 95.247 us; speedup vs baseline: 1.0139x; 1.0139x over previous
//
#include <hip/hip_runtime.h>
#include <hip/hip_bf16.h>
#include <cstdint>
#include <cstddef>

// ---------------------------------------------------------------------------
// Types / helpers
// ---------------------------------------------------------------------------
typedef __bf16 bf16x8 __attribute__((ext_vector_type(8)));
typedef float  f32x4  __attribute__((ext_vector_type(4)));

template <int V> struct IC { static constexpr int value = V; };

__device__ __forceinline__ unsigned short f2bf(float f) {
    unsigned x = __float_as_uint(f);
    return (unsigned short)((x + 0x7fffu + ((x >> 16) & 1u)) >> 16); // RNE
}

__device__ __forceinline__ f32x4 mfma16(bf16x8 a, bf16x8 b, f32x4 c) {
    return __builtin_amdgcn_mfma_f32_16x16x32_bf16(a, b, c, 0, 0, 0);
}

// XOR-swizzled byte offset inside an LDS tile with 128-byte rows (64-col bf16).
__device__ __forceinline__ int swz(int row, int col) {
    return row * 128 + ((((col >> 3) ^ (row & 7)) << 4) | ((col & 7) << 1));
}

// BK-parameterized tile swizzle. BK=64: 8 slots/row. BK=32: 4 slots/row.
template <int BK>
__device__ __forceinline__ int tswz(int row, int col) {
    if constexpr (BK == 64)
        return row * 128 + ((((col >> 3) ^ (row & 7)) << 4) | ((col & 7) << 1));
    else
        return row * 64 + ((((col >> 3) ^ ((row >> 1) & 3)) << 4) | ((col & 7) << 1));
}

// global -> LDS direct copy, 16B per lane; lds ptr must be wave-uniform base.
#define GLDS16(g, l)                                                          \
    __builtin_amdgcn_global_load_lds(                                         \
        (const __attribute__((address_space(1))) void*)(g),                   \
        (__attribute__((address_space(3))) void*)(l), 16, 0, 0)

// ---------------------------------------------------------------------------
// Combined prep: blocks [0,12288) = fp32->bf16 convert of q/k/v rows (one
// 1024-elem row per block; K/V rows >= valid_len skipped — dead downstream);
// blocks [12288,16384) = 32x32 transpose+convert tiles of the 4 weights.
// ---------------------------------------------------------------------------
__global__ __launch_bounds__(256) void k_prep(const float4* __restrict__ i0,
                                              const float4* __restrict__ i1,
                                              const float4* __restrict__ i2,
                                              ushort4* __restrict__ xout,
                                              const float* __restrict__ W0,
                                              const float* __restrict__ W1,
                                              const float* __restrict__ W2,
                                              const float* __restrict__ W3,
                                              unsigned short* __restrict__ wout,
                                              int D, const int* __restrict__ vlen) {
    __shared__ float tile[32][33];
    const int bid = blockIdx.x;
    if (bid < 12288) {  // X convert: z = tensor, row = bid % 4096
        int z = bid >> 12, rowb = bid & 4095;
        if (z) {  // k,v: skip rows >= valid_len[batch]
            if ((rowb & 1023) >= vlen[rowb >> 10]) return;
        }
        const float4* in = (z == 0) ? i0 : (z == 1) ? i1 : i2;
        int i = rowb * 256 + threadIdx.x;
        float4 v = in[i];
        ushort4 o;
        o.x = f2bf(v.x); o.y = f2bf(v.y); o.z = f2bf(v.z); o.w = f2bf(v.w);
        xout[(size_t)z * 1048576 + i] = o;
    } else {            // weight transpose+convert
        int wid = bid - 12288;
        int z = wid >> 10, t2 = wid & 1023;
        int bx = t2 & 31, by = t2 >> 5;
        const float* W = (z == 0) ? W0 : (z == 1) ? W1 : (z == 2) ? W2 : W3;
        unsigned short* Wt = wout + (size_t)z * D * D;
        int c0 = bx * 32, r0 = by * 32;
        int tr = threadIdx.x >> 5, tc = threadIdx.x & 31;
#pragma unroll
        for (int i = 0; i < 4; i++)
            tile[tr + 8 * i][tc] = W[(size_t)(r0 + tr + 8 * i) * D + c0 + tc];
        __syncthreads();
#pragma unroll
        for (int i = 0; i < 4; i++)
            Wt[(size_t)(c0 + tr + 8 * i) * D + r0 + tc] = f2bf(tile[tc][tr + 8 * i]);
    }
}

// ---------------------------------------------------------------------------
// 256x256-tile 8-phase bf16 GEMM (batched over z=QKV): P_z = X_z * Wt_z^T.
// 512 thr / 8 waves (2M x 4N); wave tile 128x64; BK=64, 2 K-tiles/iter;
// 128 KB LDS (2 tile buffers, XOR-swizzled); counted vmcnt(4) at phases 4/8.
// launch_bounds (512,1): LDS already caps at 1 block/CU; min-waves=1 gives
// the allocator the full 512-VGPR budget (no forced spills in the K-loop).
// ---------------------------------------------------------------------------
__global__ __launch_bounds__(512, 1) void k_gemm8(const unsigned short* __restrict__ A0,
                                                  const unsigned short* __restrict__ Bt0,
                                                  unsigned short* __restrict__ C0,
                                                  int M, int N, int K,
                                                  size_t aStr, size_t bStr, size_t cStr,
                                                  const int* __restrict__ vlen) {
    __shared__ unsigned short As[2][256 * 64];  // 32 KB each
    __shared__ unsigned short Bs[2][256 * 64];

    const int gxy = gridDim.x * gridDim.y;
    const int nwg = gxy * gridDim.z;
    int wgid = blockIdx.z * gxy + blockIdx.y * gridDim.x + blockIdx.x;
    int sid = (wgid & 7) * (nwg >> 3) + (wgid >> 3);
    const int bz = sid / gxy;
    int rem = sid - bz * gxy;
    const int by = rem / gridDim.x;
    const int bx = rem - by * gridDim.x;

    if (bz >= 1) {
        int srow = (by << 8) & 1023;
        int bb = (by << 8) >> 10;
        if (srow >= vlen[bb]) return;
    }

    const unsigned short* A  = A0 + (size_t)bz * aStr;
    const unsigned short* Bt = Bt0 + (size_t)bz * bStr;
    unsigned short* C = C0 + (size_t)bz * cStr;

    const int t = threadIdx.x, lane = t & 63, w = t >> 6;
    const int wr = w >> 2, wc = w & 3;
    const int l15 = lane & 15, l4 = lane >> 4;
    const int brow = by * 256, bcol = bx * 256;

    f32x4 acc[8][4];
#pragma unroll
    for (int m = 0; m < 8; m++)
#pragma unroll
        for (int n = 0; n < 4; n++) acc[m][n] = f32x4{0.f, 0.f, 0.f, 0.f};

    auto stA = [&](int buf, int kt, int h) {
#pragma unroll
        for (int j = 0; j < 2; j++) {
            int c = h * 1024 + j * 512 + t;
            int row = c >> 3, slot = c & 7;
            GLDS16(A + (size_t)(brow + row) * K + kt * 64 + ((slot ^ (row & 7)) << 3),
                   (char*)As[buf] + (size_t)(h * 1024 + j * 512 + w * 64) * 16);
        }
    };
    auto stB = [&](int buf, int kt, int h) {
#pragma unroll
        for (int j = 0; j < 2; j++) {
            int c = h * 1024 + j * 512 + t;
            int row = c >> 3, slot = c & 7;
            GLDS16(Bt + (size_t)(bcol + row) * K + kt * 64 + ((slot ^ (row & 7)) << 3),
                   (char*)Bs[buf] + (size_t)(h * 1024 + j * 512 + w * 64) * 16);
        }
    };

    bf16x8 b[4][2];

    auto phase = [&](auto BUFC, auto GC, auto RBC, auto stage, auto VMC) {
        constexpr int BUF = BUFC.value, G = GC.value, VM = VMC.value;
        constexpr bool RB = RBC.value != 0;
        bf16x8 a[2][2];
#pragma unroll
        for (int i = 0; i < 2; i++)
#pragma unroll
            for (int ks = 0; ks < 2; ks++)
                a[i][ks] = *(const bf16x8*)((const char*)As[BUF] +
                           swz(wr * 128 + (2 * G + i) * 16 + l15, ks * 32 + l4 * 8));
        if constexpr (RB) {
#pragma unroll
            for (int nf = 0; nf < 4; nf++)
#pragma unroll
                for (int ks = 0; ks < 2; ks++)
                    b[nf][ks] = *(const bf16x8*)((const char*)Bs[BUF] +
                                swz(wc * 64 + nf * 16 + l15, ks * 32 + l4 * 8));
        }
        stage();
        __builtin_amdgcn_s_barrier();
        asm volatile("s_waitcnt lgkmcnt(0)" ::: "memory");
        __builtin_amdgcn_sched_barrier(0);
        __builtin_amdgcn_s_setprio(1);
#pragma unroll
        for (int i = 0; i < 2; i++)
#pragma unroll
            for (int nf = 0; nf < 4; nf++)
#pragma unroll
                for (int ks = 0; ks < 2; ks++)
                    acc[2 * G + i][nf] = mfma16(a[i][ks], b[nf][ks], acc[2 * G + i][nf]);
        __builtin_amdgcn_s_setprio(0);
        if constexpr (VM == 0) {
            asm volatile("s_waitcnt vmcnt(0)" ::: "memory");
            __builtin_amdgcn_sched_barrier(0);
        } else if constexpr (VM > 0) {
            asm volatile("s_waitcnt vmcnt(4)" ::: "memory");
            __builtin_amdgcn_sched_barrier(0);
        }
        __builtin_amdgcn_s_barrier();
    };

    auto iter = [&](int t0, auto LASTC) {
        constexpr bool LAST = LASTC.value != 0;
        phase(IC<0>{}, IC<0>{}, IC<1>{}, [&] { stA(1, t0 + 1, 0); }, IC<-1>{});
        phase(IC<0>{}, IC<1>{}, IC<0>{}, [&] { stA(1, t0 + 1, 1); }, IC<-1>{});
        phase(IC<0>{}, IC<2>{}, IC<0>{}, [&] { if constexpr (!LAST) stB(0, t0 + 2, 0); }, IC<-1>{});
        phase(IC<0>{}, IC<3>{}, IC<0>{}, [&] { if constexpr (!LAST) stB(0, t0 + 2, 1); },
              IC<LAST ? 0 : 4>{});
        phase(IC<1>{}, IC<0>{}, IC<1>{}, [&] { if constexpr (!LAST) stA(0, t0 + 2, 0); }, IC<-1>{});
        phase(IC<1>{}, IC<1>{}, IC<0>{}, [&] { if constexpr (!LAST) stA(0, t0 + 2, 1); }, IC<-1>{});
        phase(IC<1>{}, IC<2>{}, IC<0>{}, [&] { if constexpr (!LAST) stB(1, t0 + 3, 0); }, IC<-1>{});
        phase(IC<1>{}, IC<3>{}, IC<0>{}, [&] { if constexpr (!LAST) stB(1, t0 + 3, 1); },
              IC<LAST ? -1 : 4>{});
    };

    stA(0, 0, 0); stA(0, 0, 1);
    stB(0, 0, 0); stB(0, 0, 1);
    stB(1, 1, 0); stB(1, 1, 1);
    __syncthreads();

    const int NIT = K >> 7;
    for (int it = 0; it < NIT - 1; ++it) iter(2 * it, IC<0>{});
    iter(2 * (NIT - 1), IC<1>{});

#pragma unroll
    for (int mf = 0; mf < 8; mf++)
#pragma unroll
        for (int nf = 0; nf < 4; nf++)
#pragma unroll
            for (int r = 0; r < 4; r++) {
                int row = brow + wr * 128 + mf * 16 + l4 * 4 + r;
                int col = bcol + wc * 64 + nf * 16 + l15;
                C[(size_t)row * N + col] = f2bf(acc[mf][nf][r]);
            }
}

// ---------------------------------------------------------------------------
// 2-phase GEMM (Wo): tile 128 x TN, BK=32/64, dbuf LDS, prefetch.
// ---------------------------------------------------------------------------
template <int BK, int TN, typename OutT>
__global__ __launch_bounds__(256) void k_gemm_bt(const unsigned short* __restrict__ A0,
                                                 const unsigned short* __restrict__ Bt0,
                                                 OutT* __restrict__ C0,
                                                 int M, int N, int K,
                                                 size_t aStr, size_t bStr, size_t cStr) {
    constexpr int NF = TN / 32;
    constexpr int SLOTS = BK / 8;
    constexpr int RA = BK / 16;
    constexpr int RB = TN * BK / 2048;

    __shared__ unsigned short As[2][128 * BK];
    __shared__ unsigned short Bs[2][TN * BK];

    const int gxy = gridDim.x * gridDim.y;
    const int nwg = gxy * gridDim.z;
    int wgid = blockIdx.z * gxy + blockIdx.y * gridDim.x + blockIdx.x;
    int sid = (wgid & 7) * (nwg >> 3) + (wgid >> 3);
    const int bz = sid / gxy;
    int rem = sid - bz * gxy;
    const int by = rem / gridDim.x;
    const int bx = rem - by * gridDim.x;

    const unsigned short* A  = A0 + (size_t)bz * aStr;
    const unsigned short* Bt = Bt0 + (size_t)bz * bStr;
    OutT* C = C0 + (size_t)bz * cStr;

    const int t = threadIdx.x;
    const int lane = t & 63, wave = t >> 6;
    const int wr = wave >> 1, wc = wave & 1;
    const int l15 = lane & 15, l4 = lane >> 4;
    const int brow = by * 128, bcol = bx * TN;

    f32x4 zero = {0.f, 0.f, 0.f, 0.f};
    f32x4 acc[4][NF];
#pragma unroll
    for (int m = 0; m < 4; m++)
#pragma unroll
        for (int n = 0; n < NF; n++) acc[m][n] = zero;

    auto stage = [&](int buf, int k0) {
#pragma unroll
        for (int i = 0; i < RA; i++) {
            int c = t + i * 256;
            int row = c / SLOTS;
            int slot = c & (SLOTS - 1);
            int gx = (BK == 64) ? (row & 7) : ((row >> 1) & 3);
            GLDS16(A + (size_t)(brow + row) * K + k0 + (slot ^ gx) * 8,
                   (char*)As[buf] + (size_t)((wave * 64 + i * 256) * 16));
        }
#pragma unroll
        for (int i = 0; i < RB; i++) {
            int c = t + i * 256;
            int row = c / SLOTS;
            int slot = c & (SLOTS - 1);
            int gx = (BK == 64) ? (row & 7) : ((row >> 1) & 3);
            GLDS16(Bt + (size_t)(bcol + row) * K + k0 + (slot ^ gx) * 8,
                   (char*)Bs[buf] + (size_t)((wave * 64 + i * 256) * 16));
        }
    };

    auto compute = [&](int buf) {
#pragma unroll
        for (int ks = 0; ks < BK / 32; ++ks) {
            bf16x8 a[4], b[NF];
#pragma unroll
            for (int m = 0; m < 4; m++) {
                int row = wr * 64 + m * 16 + l15;
                a[m] = *(const bf16x8*)((const char*)As[buf] + tswz<BK>(row, ks * 32 + l4 * 8));
            }
#pragma unroll
            for (int n = 0; n < NF; n++) {
                int row = wc * (TN / 2) + n * 16 + l15;
                b[n] = *(const bf16x8*)((const char*)Bs[buf] + tswz<BK>(row, ks * 32 + l4 * 8));
            }
            __builtin_amdgcn_s_setprio(1);
#pragma unroll
            for (int m = 0; m < 4; m++)
#pragma unroll
                for (int n = 0; n < NF; n++)
                    acc[m][n] = mfma16(a[m], b[n], acc[m][n]);
            __builtin_amdgcn_s_setprio(0);
        }
    };

    const int NT = K / BK;
    stage(0, 0);
    __syncthreads();
    int cur = 0;
    for (int kt = 0; kt < NT - 1; ++kt) {
        stage(cur ^ 1, (kt + 1) * BK);
        compute(cur);
        __syncthreads();
        cur ^= 1;
    }
    compute(cur);

#pragma unroll
    for (int m = 0; m < 4; m++)
#pragma unroll
        for (int n = 0; n < NF; n++)
#pragma unroll
            for (int r = 0; r < 4; r++) {
                int row = brow + wr * 64 + m * 16 + l4 * 4 + r;
                int col = bcol + wc * (TN / 2) + n * 16 + l15;
                float v = acc[m][n][r];
                if constexpr (sizeof(OutT) == 2)
                    ((unsigned short*)C)[(size_t)row * N + col] = f2bf(v);
                else
                    C[(size_t)row * N + col] = v;
            }
}

// ---------------------------------------------------------------------------
// Fused flash attention, one block per (b, h, 64 q-rows). 256 thr, 4 waves.
// (round-15 structure: 40KB LDS -> 4 blocks/CU TLP)
// ---------------------------------------------------------------------------
__global__ __launch_bounds__(256) void k_attn(const unsigned short* __restrict__ Qp,
                                              const unsigned short* __restrict__ Kp,
                                              const unsigned short* __restrict__ Vp,
                                              const int* __restrict__ valid_lens,
                                              unsigned short* __restrict__ AO,
                                              int S, int D) {
    __shared__ unsigned short Ks[2][64 * 64];
    __shared__ unsigned short Vt[2][64 * 64];
    __shared__ unsigned short Ps[64 * 64];

    const int t = threadIdx.x, lane = t & 63, w = t >> 6;
    const int l15 = lane & 15, l4 = lane >> 4;
    const int b = blockIdx.z, h = blockIdx.y, q0 = blockIdx.x * 64;
    const int vl = valid_lens[b];
    const size_t baserow = (size_t)b * S;
    const int hcol = h * 64;
    const int vr = t >> 2, vc0 = (t & 3) * 16;

    bf16x8 aq[2];
#pragma unroll
    for (int ks = 0; ks < 2; ++ks)
        aq[ks] = *(const bf16x8*)&Qp[(baserow + q0 + w * 16 + l15) * D + hcol + ks * 32 + l4 * 8];

    f32x4 zero = {0.f, 0.f, 0.f, 0.f};
    f32x4 oacc[4];
#pragma unroll
    for (int nf = 0; nf < 4; nf++) oacc[nf] = zero;
    float m_run[4], l_run[4];
#pragma unroll
    for (int r = 0; r < 4; r++) { m_run[r] = -1e30f; l_run[r] = 0.f; }

    auto stageK = [&](int buf, int kv0) {
#pragma unroll
        for (int i = 0; i < 2; i++) {
            int c = t + i * 256;
            int row = c >> 3;
            int gcol = ((c & 7) ^ (row & 7)) * 8;
            const unsigned short* gk = Kp + (baserow + kv0 + row) * D + hcol + gcol;
            GLDS16(gk, (char*)Ks[buf] + (size_t)((w * 64 + i * 256) * 16));
        }
    };
    auto loadV = [&](int kv0, bf16x8& v0, bf16x8& v1) {
        const unsigned short* gv = Vp + (baserow + kv0 + vr) * D + hcol + vc0;
        v0 = *(const bf16x8*)gv;
        v1 = *(const bf16x8*)(gv + 8);
    };
    auto writeV = [&](int buf, bf16x8 v0, bf16x8 v1) {
#pragma unroll
        for (int i = 0; i < 8; i++) {
            union { __bf16 h; unsigned short u; } c0, c1;
            c0.h = v0[i]; c1.h = v1[i];
            *(unsigned short*)((char*)Vt[buf] + swz(vc0 + i, vr)) = c0.u;
            *(unsigned short*)((char*)Vt[buf] + swz(vc0 + 8 + i, vr)) = c1.u;
        }
    };

    const int nt = (vl + 63) >> 6;
    stageK(0, 0);
    {
        bf16x8 v0, v1;
        loadV(0, v0, v1);
        writeV(0, v0, v1);
    }

    int cur = 0;
    for (int tt = 0; tt < nt; ++tt) {
        __syncthreads();

        bf16x8 nv0, nv1;
        const bool have_next = (tt + 1) < nt;
        if (have_next) {
            stageK(cur ^ 1, (tt + 1) * 64);
            loadV((tt + 1) * 64, nv0, nv1);
        }

        const int kv0 = tt * 64;
        f32x4 sacc[4];
#pragma unroll
        for (int f = 0; f < 4; f++) {
            sacc[f] = zero;
#pragma unroll
            for (int ks = 0; ks < 2; ++ks) {
                bf16x8 bk = *(const bf16x8*)((const char*)Ks[cur] + swz(f * 16 + l15, ks * 32 + l4 * 8));
                __builtin_amdgcn_s_setprio(1);
                sacc[f] = mfma16(aq[ks], bk, sacc[f]);
                __builtin_amdgcn_s_setprio(0);
            }
        }
#pragma unroll
        for (int f = 0; f < 4; f++) {
            bool masked = (kv0 + f * 16 + l15) >= vl;
#pragma unroll
            for (int r = 0; r < 4; r++) {
                float s = sacc[f][r] * 0.125f;
                sacc[f][r] = masked ? -1e30f : s;
            }
        }
        float mx[4];
#pragma unroll
        for (int r = 0; r < 4; r++)
            mx[r] = fmaxf(fmaxf(sacc[0][r], sacc[1][r]), fmaxf(sacc[2][r], sacc[3][r]));
#pragma unroll
        for (int off = 1; off < 16; off <<= 1)
#pragma unroll
            for (int r = 0; r < 4; r++) mx[r] = fmaxf(mx[r], __shfl_xor(mx[r], off));

        float nm[4], alpha[4], rs[4];
#pragma unroll
        for (int r = 0; r < 4; r++) {
            nm[r] = fmaxf(m_run[r], mx[r]);
            alpha[r] = __expf(m_run[r] - nm[r]);
            m_run[r] = nm[r];
            rs[r] = 0.f;
        }
#pragma unroll
        for (int f = 0; f < 4; f++)
#pragma unroll
            for (int r = 0; r < 4; r++) {
                float p = __expf(sacc[f][r] - nm[r]);
                rs[r] += p;
                *(unsigned short*)((char*)Ps + swz(w * 16 + l4 * 4 + r, f * 16 + l15)) = f2bf(p);
            }
#pragma unroll
        for (int off = 1; off < 16; off <<= 1)
#pragma unroll
            for (int r = 0; r < 4; r++) rs[r] += __shfl_xor(rs[r], off);
#pragma unroll
        for (int r = 0; r < 4; r++) l_run[r] = l_run[r] * alpha[r] + rs[r];
#pragma unroll
        for (int nf = 0; nf < 4; nf++)
#pragma unroll
            for (int r = 0; r < 4; r++) oacc[nf][r] *= alpha[r];

        if (have_next) writeV(cur ^ 1, nv0, nv1);

        asm volatile("s_waitcnt lgkmcnt(0)" ::: "memory");
        __builtin_amdgcn_sched_barrier(0);

        bf16x8 ap[2];
#pragma unroll
        for (int ks = 0; ks < 2; ++ks)
            ap[ks] = *(const bf16x8*)((const char*)Ps + swz(w * 16 + l15, ks * 32 + l4 * 8));
#pragma unroll
        for (int nf = 0; nf < 4; nf++)
#pragma unroll
            for (int ks = 0; ks < 2; ++ks) {
                bf16x8 bv = *(const bf16x8*)((const char*)Vt[cur] + swz(nf * 16 + l15, ks * 32 + l4 * 8));
                __builtin_amdgcn_s_setprio(1);
                oacc[nf] = mfma16(ap[ks], bv, oacc[nf]);
                __builtin_amdgcn_s_setprio(0);
            }
        cur ^= 1;
    }

#pragma unroll
    for (int nf = 0; nf < 4; nf++)
#pragma unroll
        for (int r = 0; r < 4; r++) {
            float v = oacc[nf][r] / l_run[r];
            int row = q0 + w * 16 + l4 * 4 + r;
            AO[(baserow + row) * D + hcol + nf * 16 + l15] = f2bf(v);
        }
}

// ---------------------------------------------------------------------------
// Launch
// ---------------------------------------------------------------------------
extern "C" void kernel_launch(void* const* d_in, const int* in_sizes, int n_in,
                              void* d_out, int out_size, void* d_ws, size_t ws_size,
                              hipStream_t stream) {
    const float* q  = (const float*)d_in[0];
    const float* k  = (const float*)d_in[1];
    const float* v  = (const float*)d_in[2];
    const int* vlen = (const int*)d_in[3];
    const float* Wq = (const float*)d_in[4];
    const float* Wk = (const float*)d_in[5];
    const float* Wv = (const float*)d_in[6];
    const float* Wo = (const float*)d_in[7];

    const int B = in_sizes[3];        // 4
    const int D = 1024, S = 1024, H = 16;  // fixed problem instance (dh=64)
    const int M = B * S;              // 4096
    const size_t MB = 1u << 20;

    char* ws = (char*)d_ws;
    unsigned short* X   = (unsigned short*)(ws + 0 * MB);   // Xq,Xk,Xv contiguous (8MB each)
    unsigned short* Wt  = (unsigned short*)(ws + 24 * MB);  // Wtq,Wtk,Wtv,Wto contiguous (2MB each)
    unsigned short* Wto = (unsigned short*)(ws + 30 * MB);
    unsigned short* P   = (unsigned short*)(ws + 32 * MB);  // Qp,Kp,Vp contiguous (8MB each)
    unsigned short* Qp  = P;
    unsigned short* Kp  = P + 4 * 1024 * 1024;
    unsigned short* Vp  = P + 8 * 1024 * 1024;
    unsigned short* AO  = X;  // safe: X dead after QKV projections

    // prep: X converts (K/V dead rows skipped) + weight transposes, 1 launch
    k_prep<<<dim3(16384), 256, 0, stream>>>(
        (const float4*)q, (const float4*)k, (const float4*)v, (ushort4*)X,
        Wq, Wk, Wv, Wo, Wt, D, vlen);

    // QKV projections: 256^2 8-phase kernel, z=3 (192 blocks), dead K/V tiles skipped
    const size_t xStr = (size_t)M * D, wStr = (size_t)D * D;
    k_gemm8<<<dim3(D / 256, M / 256, 3), 512, 0, stream>>>(
        X, Wt, P, M, D, D, xStr, wStr, xStr, vlen);

    // attention: 64 q-rows per block (1024 blocks, 4/CU TLP)
    k_attn<<<dim3(S / 64, H, B), 256, 0, stream>>>(Qp, Kp, Vp, vlen, AO, S, D);

    // output projection (fp32 out): tile 128x64, BK=64, 512 blocks = 2/CU.
    k_gemm_bt<64, 64, float><<<dim3(D / 64, M / 128, 1), 256, 0, stream>>>(
        AO, Wto, (float*)d_out, M, D, D, 0, 0, 0);
}

// Round 19
// 92.830 us; speedup vs baseline: 1.0403x; 1.0260x over previous
//
#include <hip/hip_runtime.h>
#include <hip/hip_bf16.h>
#include <cstdint>
#include <cstddef>

// ---------------------------------------------------------------------------
// Types / helpers
// ---------------------------------------------------------------------------
typedef __bf16 bf16x8 __attribute__((ext_vector_type(8)));
typedef float  f32x4  __attribute__((ext_vector_type(4)));

template <int V> struct IC { static constexpr int value = V; };

__device__ __forceinline__ unsigned short f2bf(float f) {
    unsigned x = __float_as_uint(f);
    return (unsigned short)((x + 0x7fffu + ((x >> 16) & 1u)) >> 16); // RNE
}

__device__ __forceinline__ f32x4 mfma16(bf16x8 a, bf16x8 b, f32x4 c) {
    return __builtin_amdgcn_mfma_f32_16x16x32_bf16(a, b, c, 0, 0, 0);
}

// XOR-swizzled byte offset inside an LDS tile with 128-byte rows (64-col bf16).
__device__ __forceinline__ int swz(int row, int col) {
    return row * 128 + ((((col >> 3) ^ (row & 7)) << 4) | ((col & 7) << 1));
}

// BK-parameterized tile swizzle. BK=64: 8 slots/row. BK=32: 4 slots/row.
template <int BK>
__device__ __forceinline__ int tswz(int row, int col) {
    if constexpr (BK == 64)
        return row * 128 + ((((col >> 3) ^ (row & 7)) << 4) | ((col & 7) << 1));
    else
        return row * 64 + ((((col >> 3) ^ ((row >> 1) & 3)) << 4) | ((col & 7) << 1));
}

// global -> LDS direct copy, 16B per lane; lds ptr must be wave-uniform base.
#define GLDS16(g, l)                                                          \
    __builtin_amdgcn_global_load_lds(                                         \
        (const __attribute__((address_space(1))) void*)(g),                   \
        (__attribute__((address_space(3))) void*)(l), 16, 0, 0)

// ---------------------------------------------------------------------------
// Combined prep: blocks [0,12288) = fp32->bf16 convert of q/k/v rows (one
// 1024-elem row per block; K/V rows >= valid_len skipped — dead downstream);
// blocks [12288,16384) = 32x32 transpose+convert tiles of the 4 weights.
// ---------------------------------------------------------------------------
__global__ __launch_bounds__(256) void k_prep(const float4* __restrict__ i0,
                                              const float4* __restrict__ i1,
                                              const float4* __restrict__ i2,
                                              ushort4* __restrict__ xout,
                                              const float* __restrict__ W0,
                                              const float* __restrict__ W1,
                                              const float* __restrict__ W2,
                                              const float* __restrict__ W3,
                                              unsigned short* __restrict__ wout,
                                              int D, const int* __restrict__ vlen) {
    __shared__ float tile[32][33];
    const int bid = blockIdx.x;
    if (bid < 12288) {  // X convert: z = tensor, row = bid % 4096
        int z = bid >> 12, rowb = bid & 4095;
        if (z) {  // k,v: skip rows >= valid_len[batch]
            if ((rowb & 1023) >= vlen[rowb >> 10]) return;
        }
        const float4* in = (z == 0) ? i0 : (z == 1) ? i1 : i2;
        int i = rowb * 256 + threadIdx.x;
        float4 v = in[i];
        ushort4 o;
        o.x = f2bf(v.x); o.y = f2bf(v.y); o.z = f2bf(v.z); o.w = f2bf(v.w);
        xout[(size_t)z * 1048576 + i] = o;
    } else {            // weight transpose+convert
        int wid = bid - 12288;
        int z = wid >> 10, t2 = wid & 1023;
        int bx = t2 & 31, by = t2 >> 5;
        const float* W = (z == 0) ? W0 : (z == 1) ? W1 : (z == 2) ? W2 : W3;
        unsigned short* Wt = wout + (size_t)z * D * D;
        int c0 = bx * 32, r0 = by * 32;
        int tr = threadIdx.x >> 5, tc = threadIdx.x & 31;
#pragma unroll
        for (int i = 0; i < 4; i++)
            tile[tr + 8 * i][tc] = W[(size_t)(r0 + tr + 8 * i) * D + c0 + tc];
        __syncthreads();
#pragma unroll
        for (int i = 0; i < 4; i++)
            Wt[(size_t)(c0 + tr + 8 * i) * D + r0 + tc] = f2bf(tile[tc][tr + 8 * i]);
    }
}

// ---------------------------------------------------------------------------
// 256x256-tile 8-phase bf16 GEMM (batched over z=QKV): P_z = X_z * Wt_z^T.
// 512 thr / 8 waves (2M x 4N); wave tile 128x64; BK=64, 2 K-tiles/iter;
// 128 KB LDS (2 tile buffers, XOR-swizzled); counted vmcnt(4) at phases 4/8.
// ---------------------------------------------------------------------------
__global__ __launch_bounds__(512, 1) void k_gemm8(const unsigned short* __restrict__ A0,
                                                  const unsigned short* __restrict__ Bt0,
                                                  unsigned short* __restrict__ C0,
                                                  int M, int N, int K,
                                                  size_t aStr, size_t bStr, size_t cStr,
                                                  const int* __restrict__ vlen) {
    __shared__ unsigned short As[2][256 * 64];  // 32 KB each
    __shared__ unsigned short Bs[2][256 * 64];

    const int gxy = gridDim.x * gridDim.y;
    const int nwg = gxy * gridDim.z;
    int wgid = blockIdx.z * gxy + blockIdx.y * gridDim.x + blockIdx.x;
    int sid = (wgid & 7) * (nwg >> 3) + (wgid >> 3);
    const int bz = sid / gxy;
    int rem = sid - bz * gxy;
    const int by = rem / gridDim.x;
    const int bx = rem - by * gridDim.x;

    if (bz >= 1) {
        int srow = (by << 8) & 1023;
        int bb = (by << 8) >> 10;
        if (srow >= vlen[bb]) return;
    }

    const unsigned short* A  = A0 + (size_t)bz * aStr;
    const unsigned short* Bt = Bt0 + (size_t)bz * bStr;
    unsigned short* C = C0 + (size_t)bz * cStr;

    const int t = threadIdx.x, lane = t & 63, w = t >> 6;
    const int wr = w >> 2, wc = w & 3;
    const int l15 = lane & 15, l4 = lane >> 4;
    const int brow = by * 256, bcol = bx * 256;

    f32x4 acc[8][4];
#pragma unroll
    for (int m = 0; m < 8; m++)
#pragma unroll
        for (int n = 0; n < 4; n++) acc[m][n] = f32x4{0.f, 0.f, 0.f, 0.f};

    auto stA = [&](int buf, int kt, int h) {
#pragma unroll
        for (int j = 0; j < 2; j++) {
            int c = h * 1024 + j * 512 + t;
            int row = c >> 3, slot = c & 7;
            GLDS16(A + (size_t)(brow + row) * K + kt * 64 + ((slot ^ (row & 7)) << 3),
                   (char*)As[buf] + (size_t)(h * 1024 + j * 512 + w * 64) * 16);
        }
    };
    auto stB = [&](int buf, int kt, int h) {
#pragma unroll
        for (int j = 0; j < 2; j++) {
            int c = h * 1024 + j * 512 + t;
            int row = c >> 3, slot = c & 7;
            GLDS16(Bt + (size_t)(bcol + row) * K + kt * 64 + ((slot ^ (row & 7)) << 3),
                   (char*)Bs[buf] + (size_t)(h * 1024 + j * 512 + w * 64) * 16);
        }
    };

    bf16x8 b[4][2];

    auto phase = [&](auto BUFC, auto GC, auto RBC, auto stage, auto VMC) {
        constexpr int BUF = BUFC.value, G = GC.value, VM = VMC.value;
        constexpr bool RB = RBC.value != 0;
        bf16x8 a[2][2];
#pragma unroll
        for (int i = 0; i < 2; i++)
#pragma unroll
            for (int ks = 0; ks < 2; ks++)
                a[i][ks] = *(const bf16x8*)((const char*)As[BUF] +
                           swz(wr * 128 + (2 * G + i) * 16 + l15, ks * 32 + l4 * 8));
        if constexpr (RB) {
#pragma unroll
            for (int nf = 0; nf < 4; nf++)
#pragma unroll
                for (int ks = 0; ks < 2; ks++)
                    b[nf][ks] = *(const bf16x8*)((const char*)Bs[BUF] +
                                swz(wc * 64 + nf * 16 + l15, ks * 32 + l4 * 8));
        }
        stage();
        __builtin_amdgcn_s_barrier();
        asm volatile("s_waitcnt lgkmcnt(0)" ::: "memory");
        __builtin_amdgcn_sched_barrier(0);
        __builtin_amdgcn_s_setprio(1);
#pragma unroll
        for (int i = 0; i < 2; i++)
#pragma unroll
            for (int nf = 0; nf < 4; nf++)
#pragma unroll
                for (int ks = 0; ks < 2; ks++)
                    acc[2 * G + i][nf] = mfma16(a[i][ks], b[nf][ks], acc[2 * G + i][nf]);
        __builtin_amdgcn_s_setprio(0);
        if constexpr (VM == 0) {
            asm volatile("s_waitcnt vmcnt(0)" ::: "memory");
            __builtin_amdgcn_sched_barrier(0);
        } else if constexpr (VM > 0) {
            asm volatile("s_waitcnt vmcnt(4)" ::: "memory");
            __builtin_amdgcn_sched_barrier(0);
        }
        __builtin_amdgcn_s_barrier();
    };

    auto iter = [&](int t0, auto LASTC) {
        constexpr bool LAST = LASTC.value != 0;
        phase(IC<0>{}, IC<0>{}, IC<1>{}, [&] { stA(1, t0 + 1, 0); }, IC<-1>{});
        phase(IC<0>{}, IC<1>{}, IC<0>{}, [&] { stA(1, t0 + 1, 1); }, IC<-1>{});
        phase(IC<0>{}, IC<2>{}, IC<0>{}, [&] { if constexpr (!LAST) stB(0, t0 + 2, 0); }, IC<-1>{});
        phase(IC<0>{}, IC<3>{}, IC<0>{}, [&] { if constexpr (!LAST) stB(0, t0 + 2, 1); },
              IC<LAST ? 0 : 4>{});
        phase(IC<1>{}, IC<0>{}, IC<1>{}, [&] { if constexpr (!LAST) stA(0, t0 + 2, 0); }, IC<-1>{});
        phase(IC<1>{}, IC<1>{}, IC<0>{}, [&] { if constexpr (!LAST) stA(0, t0 + 2, 1); }, IC<-1>{});
        phase(IC<1>{}, IC<2>{}, IC<0>{}, [&] { if constexpr (!LAST) stB(1, t0 + 3, 0); }, IC<-1>{});
        phase(IC<1>{}, IC<3>{}, IC<0>{}, [&] { if constexpr (!LAST) stB(1, t0 + 3, 1); },
              IC<LAST ? -1 : 4>{});
    };

    stA(0, 0, 0); stA(0, 0, 1);
    stB(0, 0, 0); stB(0, 0, 1);
    stB(1, 1, 0); stB(1, 1, 1);
    __syncthreads();

    const int NIT = K >> 7;
    for (int it = 0; it < NIT - 1; ++it) iter(2 * it, IC<0>{});
    iter(2 * (NIT - 1), IC<1>{});

#pragma unroll
    for (int mf = 0; mf < 8; mf++)
#pragma unroll
        for (int nf = 0; nf < 4; nf++)
#pragma unroll
            for (int r = 0; r < 4; r++) {
                int row = brow + wr * 128 + mf * 16 + l4 * 4 + r;
                int col = bcol + wc * 64 + nf * 16 + l15;
                C[(size_t)row * N + col] = f2bf(acc[mf][nf][r]);
            }
}

// ---------------------------------------------------------------------------
// 2-phase GEMM (Wo): tile TM x TN, BK=32/64, dbuf LDS, prefetch.
// 256 thr / 4 waves (2M x 2N); wave tile (TM/2) x (TN/2).
// ---------------------------------------------------------------------------
template <int BK, int TM, int TN, typename OutT>
__global__ __launch_bounds__(256) void k_gemm_bt(const unsigned short* __restrict__ A0,
                                                 const unsigned short* __restrict__ Bt0,
                                                 OutT* __restrict__ C0,
                                                 int M, int N, int K,
                                                 size_t aStr, size_t bStr, size_t cStr) {
    constexpr int NM = TM / 32;            // A fragments per wave
    constexpr int NF = TN / 32;            // B fragments per wave
    constexpr int SLOTS = BK / 8;
    constexpr int RA = TM * BK / 2048;     // staging rounds for A
    constexpr int RB = TN * BK / 2048;     // staging rounds for B

    __shared__ unsigned short As[2][TM * BK];
    __shared__ unsigned short Bs[2][TN * BK];

    const int gxy = gridDim.x * gridDim.y;
    const int nwg = gxy * gridDim.z;
    int wgid = blockIdx.z * gxy + blockIdx.y * gridDim.x + blockIdx.x;
    int sid = (wgid & 7) * (nwg >> 3) + (wgid >> 3);
    const int bz = sid / gxy;
    int rem = sid - bz * gxy;
    const int by = rem / gridDim.x;
    const int bx = rem - by * gridDim.x;

    const unsigned short* A  = A0 + (size_t)bz * aStr;
    const unsigned short* Bt = Bt0 + (size_t)bz * bStr;
    OutT* C = C0 + (size_t)bz * cStr;

    const int t = threadIdx.x;
    const int lane = t & 63, wave = t >> 6;
    const int wr = wave >> 1, wc = wave & 1;
    const int l15 = lane & 15, l4 = lane >> 4;
    const int brow = by * TM, bcol = bx * TN;

    f32x4 zero = {0.f, 0.f, 0.f, 0.f};
    f32x4 acc[NM][NF];
#pragma unroll
    for (int m = 0; m < NM; m++)
#pragma unroll
        for (int n = 0; n < NF; n++) acc[m][n] = zero;

    auto stage = [&](int buf, int k0) {
#pragma unroll
        for (int i = 0; i < RA; i++) {
            int c = t + i * 256;
            int row = c / SLOTS;
            int slot = c & (SLOTS - 1);
            int gx = (BK == 64) ? (row & 7) : ((row >> 1) & 3);
            GLDS16(A + (size_t)(brow + row) * K + k0 + (slot ^ gx) * 8,
                   (char*)As[buf] + (size_t)((wave * 64 + i * 256) * 16));
        }
#pragma unroll
        for (int i = 0; i < RB; i++) {
            int c = t + i * 256;
            int row = c / SLOTS;
            int slot = c & (SLOTS - 1);
            int gx = (BK == 64) ? (row & 7) : ((row >> 1) & 3);
            GLDS16(Bt + (size_t)(bcol + row) * K + k0 + (slot ^ gx) * 8,
                   (char*)Bs[buf] + (size_t)((wave * 64 + i * 256) * 16));
        }
    };

    auto compute = [&](int buf) {
#pragma unroll
        for (int ks = 0; ks < BK / 32; ++ks) {
            bf16x8 a[NM], b[NF];
#pragma unroll
            for (int m = 0; m < NM; m++) {
                int row = wr * (TM / 2) + m * 16 + l15;
                a[m] = *(const bf16x8*)((const char*)As[buf] + tswz<BK>(row, ks * 32 + l4 * 8));
            }
#pragma unroll
            for (int n = 0; n < NF; n++) {
                int row = wc * (TN / 2) + n * 16 + l15;
                b[n] = *(const bf16x8*)((const char*)Bs[buf] + tswz<BK>(row, ks * 32 + l4 * 8));
            }
            __builtin_amdgcn_s_setprio(1);
#pragma unroll
            for (int m = 0; m < NM; m++)
#pragma unroll
                for (int n = 0; n < NF; n++)
                    acc[m][n] = mfma16(a[m], b[n], acc[m][n]);
            __builtin_amdgcn_s_setprio(0);
        }
    };

    const int NT = K / BK;
    stage(0, 0);
    __syncthreads();
    int cur = 0;
    for (int kt = 0; kt < NT - 1; ++kt) {
        stage(cur ^ 1, (kt + 1) * BK);
        compute(cur);
        __syncthreads();
        cur ^= 1;
    }
    compute(cur);

#pragma unroll
    for (int m = 0; m < NM; m++)
#pragma unroll
        for (int n = 0; n < NF; n++)
#pragma unroll
            for (int r = 0; r < 4; r++) {
                int row = brow + wr * (TM / 2) + m * 16 + l4 * 4 + r;
                int col = bcol + wc * (TN / 2) + n * 16 + l15;
                float v = acc[m][n][r];
                if constexpr (sizeof(OutT) == 2)
                    ((unsigned short*)C)[(size_t)row * N + col] = f2bf(v);
                else
                    C[(size_t)row * N + col] = v;
            }
}

// ---------------------------------------------------------------------------
// Fused flash attention, one block per (b, h, 64 q-rows). 256 thr, 4 waves.
// (round-15 structure: 40KB LDS -> 4 blocks/CU TLP)
// ---------------------------------------------------------------------------
__global__ __launch_bounds__(256) void k_attn(const unsigned short* __restrict__ Qp,
                                              const unsigned short* __restrict__ Kp,
                                              const unsigned short* __restrict__ Vp,
                                              const int* __restrict__ valid_lens,
                                              unsigned short* __restrict__ AO,
                                              int S, int D) {
    __shared__ unsigned short Ks[2][64 * 64];
    __shared__ unsigned short Vt[2][64 * 64];
    __shared__ unsigned short Ps[64 * 64];

    const int t = threadIdx.x, lane = t & 63, w = t >> 6;
    const int l15 = lane & 15, l4 = lane >> 4;
    const int b = blockIdx.z, h = blockIdx.y, q0 = blockIdx.x * 64;
    const int vl = valid_lens[b];
    const size_t baserow = (size_t)b * S;
    const int hcol = h * 64;
    const int vr = t >> 2, vc0 = (t & 3) * 16;

    bf16x8 aq[2];
#pragma unroll
    for (int ks = 0; ks < 2; ++ks)
        aq[ks] = *(const bf16x8*)&Qp[(baserow + q0 + w * 16 + l15) * D + hcol + ks * 32 + l4 * 8];

    f32x4 zero = {0.f, 0.f, 0.f, 0.f};
    f32x4 oacc[4];
#pragma unroll
    for (int nf = 0; nf < 4; nf++) oacc[nf] = zero;
    float m_run[4], l_run[4];
#pragma unroll
    for (int r = 0; r < 4; r++) { m_run[r] = -1e30f; l_run[r] = 0.f; }

    auto stageK = [&](int buf, int kv0) {
#pragma unroll
        for (int i = 0; i < 2; i++) {
            int c = t + i * 256;
            int row = c >> 3;
            int gcol = ((c & 7) ^ (row & 7)) * 8;
            const unsigned short* gk = Kp + (baserow + kv0 + row) * D + hcol + gcol;
            GLDS16(gk, (char*)Ks[buf] + (size_t)((w * 64 + i * 256) * 16));
        }
    };
    auto loadV = [&](int kv0, bf16x8& v0, bf16x8& v1) {
        const unsigned short* gv = Vp + (baserow + kv0 + vr) * D + hcol + vc0;
        v0 = *(const bf16x8*)gv;
        v1 = *(const bf16x8*)(gv + 8);
    };
    auto writeV = [&](int buf, bf16x8 v0, bf16x8 v1) {
#pragma unroll
        for (int i = 0; i < 8; i++) {
            union { __bf16 h; unsigned short u; } c0, c1;
            c0.h = v0[i]; c1.h = v1[i];
            *(unsigned short*)((char*)Vt[buf] + swz(vc0 + i, vr)) = c0.u;
            *(unsigned short*)((char*)Vt[buf] + swz(vc0 + 8 + i, vr)) = c1.u;
        }
    };

    const int nt = (vl + 63) >> 6;
    stageK(0, 0);
    {
        bf16x8 v0, v1;
        loadV(0, v0, v1);
        writeV(0, v0, v1);
    }

    int cur = 0;
    for (int tt = 0; tt < nt; ++tt) {
        __syncthreads();

        bf16x8 nv0, nv1;
        const bool have_next = (tt + 1) < nt;
        if (have_next) {
            stageK(cur ^ 1, (tt + 1) * 64);
            loadV((tt + 1) * 64, nv0, nv1);
        }

        const int kv0 = tt * 64;
        f32x4 sacc[4];
#pragma unroll
        for (int f = 0; f < 4; f++) {
            sacc[f] = zero;
#pragma unroll
            for (int ks = 0; ks < 2; ++ks) {
                bf16x8 bk = *(const bf16x8*)((const char*)Ks[cur] + swz(f * 16 + l15, ks * 32 + l4 * 8));
                __builtin_amdgcn_s_setprio(1);
                sacc[f] = mfma16(aq[ks], bk, sacc[f]);
                __builtin_amdgcn_s_setprio(0);
            }
        }
#pragma unroll
        for (int f = 0; f < 4; f++) {
            bool masked = (kv0 + f * 16 + l15) >= vl;
#pragma unroll
            for (int r = 0; r < 4; r++) {
                float s = sacc[f][r] * 0.125f;
                sacc[f][r] = masked ? -1e30f : s;
            }
        }
        float mx[4];
#pragma unroll
        for (int r = 0; r < 4; r++)
            mx[r] = fmaxf(fmaxf(sacc[0][r], sacc[1][r]), fmaxf(sacc[2][r], sacc[3][r]));
#pragma unroll
        for (int off = 1; off < 16; off <<= 1)
#pragma unroll
            for (int r = 0; r < 4; r++) mx[r] = fmaxf(mx[r], __shfl_xor(mx[r], off));

        float nm[4], alpha[4], rs[4];
#pragma unroll
        for (int r = 0; r < 4; r++) {
            nm[r] = fmaxf(m_run[r], mx[r]);
            alpha[r] = __expf(m_run[r] - nm[r]);
            m_run[r] = nm[r];
            rs[r] = 0.f;
        }
#pragma unroll
        for (int f = 0; f < 4; f++)
#pragma unroll
            for (int r = 0; r < 4; r++) {
                float p = __expf(sacc[f][r] - nm[r]);
                rs[r] += p;
                *(unsigned short*)((char*)Ps + swz(w * 16 + l4 * 4 + r, f * 16 + l15)) = f2bf(p);
            }
#pragma unroll
        for (int off = 1; off < 16; off <<= 1)
#pragma unroll
            for (int r = 0; r < 4; r++) rs[r] += __shfl_xor(rs[r], off);
#pragma unroll
        for (int r = 0; r < 4; r++) l_run[r] = l_run[r] * alpha[r] + rs[r];
#pragma unroll
        for (int nf = 0; nf < 4; nf++)
#pragma unroll
            for (int r = 0; r < 4; r++) oacc[nf][r] *= alpha[r];

        if (have_next) writeV(cur ^ 1, nv0, nv1);

        asm volatile("s_waitcnt lgkmcnt(0)" ::: "memory");
        __builtin_amdgcn_sched_barrier(0);

        bf16x8 ap[2];
#pragma unroll
        for (int ks = 0; ks < 2; ++ks)
            ap[ks] = *(const bf16x8*)((const char*)Ps + swz(w * 16 + l15, ks * 32 + l4 * 8));
#pragma unroll
        for (int nf = 0; nf < 4; nf++)
#pragma unroll
            for (int ks = 0; ks < 2; ++ks) {
                bf16x8 bv = *(const bf16x8*)((const char*)Vt[cur] + swz(nf * 16 + l15, ks * 32 + l4 * 8));
                __builtin_amdgcn_s_setprio(1);
                oacc[nf] = mfma16(ap[ks], bv, oacc[nf]);
                __builtin_amdgcn_s_setprio(0);
            }
        cur ^= 1;
    }

#pragma unroll
    for (int nf = 0; nf < 4; nf++)
#pragma unroll
        for (int r = 0; r < 4; r++) {
            float v = oacc[nf][r] / l_run[r];
            int row = q0 + w * 16 + l4 * 4 + r;
            AO[(baserow + row) * D + hcol + nf * 16 + l15] = f2bf(v);
        }
}

// ---------------------------------------------------------------------------
// Launch
// ---------------------------------------------------------------------------
extern "C" void kernel_launch(void* const* d_in, const int* in_sizes, int n_in,
                              void* d_out, int out_size, void* d_ws, size_t ws_size,
                              hipStream_t stream) {
    const float* q  = (const float*)d_in[0];
    const float* k  = (const float*)d_in[1];
    const float* v  = (const float*)d_in[2];
    const int* vlen = (const int*)d_in[3];
    const float* Wq = (const float*)d_in[4];
    const float* Wk = (const float*)d_in[5];
    const float* Wv = (const float*)d_in[6];
    const float* Wo = (const float*)d_in[7];

    const int B = in_sizes[3];        // 4
    const int D = 1024, S = 1024, H = 16;  // fixed problem instance (dh=64)
    const int M = B * S;              // 4096
    const size_t MB = 1u << 20;

    char* ws = (char*)d_ws;
    unsigned short* X   = (unsigned short*)(ws + 0 * MB);   // Xq,Xk,Xv contiguous (8MB each)
    unsigned short* Wt  = (unsigned short*)(ws + 24 * MB);  // Wtq,Wtk,Wtv,Wto contiguous (2MB each)
    unsigned short* Wto = (unsigned short*)(ws + 30 * MB);
    unsigned short* P   = (unsigned short*)(ws + 32 * MB);  // Qp,Kp,Vp contiguous (8MB each)
    unsigned short* Qp  = P;
    unsigned short* Kp  = P + 4 * 1024 * 1024;
    unsigned short* Vp  = P + 8 * 1024 * 1024;
    unsigned short* AO  = X;  // safe: X dead after QKV projections

    // prep: X converts (K/V dead rows skipped) + weight transposes, 1 launch
    k_prep<<<dim3(16384), 256, 0, stream>>>(
        (const float4*)q, (const float4*)k, (const float4*)v, (ushort4*)X,
        Wq, Wk, Wv, Wo, Wt, D, vlen);

    // QKV projections: 256^2 8-phase kernel, z=3 (192 blocks), dead K/V tiles skipped
    const size_t xStr = (size_t)M * D, wStr = (size_t)D * D;
    k_gemm8<<<dim3(D / 256, M / 256, 3), 512, 0, stream>>>(
        X, Wt, P, M, D, D, xStr, wStr, xStr, vlen);

    // attention: 64 q-rows per block (1024 blocks, 4/CU TLP)
    k_attn<<<dim3(S / 64, H, B), 256, 0, stream>>>(Qp, Kp, Vp, vlen, AO, S, D);

    // output projection (fp32 out): tile 64x64, BK=64 -> 1024 blocks = 4/CU
    // resident (LDS 32KB, cap 5) — A/B vs round-18's 128x64 @ 2/CU.
    k_gemm_bt<64, 64, 64, float><<<dim3(D / 64, M / 64, 1), 256, 0, stream>>>(
        AO, Wto, (float*)d_out, M, D, D, 0, 0, 0);
}